// Round 2
// baseline (94.855 us; speedup 1.0000x reference)
//
#include <hip/hip_runtime.h>

typedef float v2f __attribute__((ext_vector_type(2)));
typedef float v4f __attribute__((ext_vector_type(4)));

#define EPS 1e-7f
#define SPW 66   // padded LDS row stride in v2f (528 B = 33*16, keeps b128 alignment)

// mantissa_map: (|v|+eps) -> mantissa m in [1,2); result = m>=1.5 ? m/2 : m  -> [0.75,1.5)
__device__ __forceinline__ float mant_map(float v) {
    float a = fabsf(v) + EPS;
    unsigned int bi = __float_as_uint(a);
    float m = __uint_as_float((bi & 0x007FFFFFu) | 0x3F800000u);
    return (m >= 1.5f) ? 0.5f * m : m;
}

// R2: one block per (b,c) plane. Block = (32,8) = 256 threads, grid (192,4).
// Thread (lx,ty): output cols {2lx,2lx+1} (lx<28), rows ty*7..ty*7+6.
// out = sum_taps u*B + v*C  with u=x, v=x/M1, B=w/M2, C=B*(M2-1).
//
// Key change vs R0/R1 (69.5 us): the inner loop previously re-read each weight
// from LDS at every use (~686 ds_read_b64 broadcasts per wave; 12 waves share
// one LDS pipe -> LDS-issue-bound). Now B factors are FORCED into SGPRs via
// readfirstlane (wave-uniform, legal as the 1-SGPR src of v_fma_f32) and C
// factors pinned into VGPRs with an asm touch. Inner loop = pure v_fma_f32.
__global__ __launch_bounds__(256, 3) void wconv_kernel(const float* __restrict__ x,
                                                       const float* __restrict__ w,
                                                       float* __restrict__ out) {
    __shared__ v2f sp[62][SPW];  // LDS row r = input row r-3; rows 0-2 / 59-61 zero (32.7 KB)
    __shared__ v2f swt[49];      // {B, C} per tap

    const int lx = threadIdx.x;   // 0..31 (col pair; active in compute if <28)
    const int ty = threadIdx.y;   // 0..7
    const int tid = ty * 32 + lx;
    const int c = blockIdx.x;
    const int b = blockIdx.y;

    const long plane = (long)(b * 192 + c) * 3136;
    const float* xp = x + plane;

    // --- fused weight prep (lanes 0..48) ---
    if (tid < 49) {
        float wv = w[c * 49 + tid];
        float M2 = mant_map(wv);
        float B = wv / M2;
        swt[tid] = (v2f){B, B * (M2 - 1.0f)};
    }

    // --- halo zero: rows 0..2 and 59..61 full (198 v2f each span) ---
    for (int t = tid; t < 3 * SPW; t += 256) {
        ((v2f*)sp)[t] = (v2f){0.f, 0.f};
        ((v2f*)sp)[59 * SPW + t] = (v2f){0.f, 0.f};
    }
    // side cols of the 56 real rows: cols 0,1,2 and 59..65 (10 v2f per row)
    for (int t = tid; t < 560; t += 256) {
        int r = t / 10, k = t % 10;
        int col = (k < 3) ? k : 56 + k;
        sp[3 + r][col] = (v2f){0.f, 0.f};
    }

    // --- interior staging: 56 rows x 14 dword4-quads = 784 tasks.
    // 3 uniform iterations per thread (issue all loads first), +16-task tail.
    {
        const int t0 = tid, t1 = tid + 256, t2 = tid + 512;
        v4f u0 = *(const v4f*)(xp + (t0 / 14) * 56 + (t0 % 14) * 4);
        v4f u1 = *(const v4f*)(xp + (t1 / 14) * 56 + (t1 % 14) * 4);
        v4f u2 = *(const v4f*)(xp + (t2 / 14) * 56 + (t2 % 14) * 4);
        v4f u3;
        if (tid < 16) u3 = *(const v4f*)(xp + ((tid + 768) / 14) * 56 + ((tid + 768) % 14) * 4);

        auto stage = [&](int t, v4f u4) {
            v2f* dst = &sp[3 + t / 14][3 + (t % 14) * 4];
            dst[0] = (v2f){u4.x, u4.x * __builtin_amdgcn_rcpf(mant_map(u4.x))};
            dst[1] = (v2f){u4.y, u4.y * __builtin_amdgcn_rcpf(mant_map(u4.y))};
            dst[2] = (v2f){u4.z, u4.z * __builtin_amdgcn_rcpf(mant_map(u4.z))};
            dst[3] = (v2f){u4.w, u4.w * __builtin_amdgcn_rcpf(mant_map(u4.w))};
        };
        stage(t0, u0);
        stage(t1, u1);
        stage(t2, u2);
        if (tid < 16) stage(tid + 768, u3);
    }
    __syncthreads();

    // --- weights -> registers, ONCE per wave (49 b64 broadcasts, not 686) ---
    // B -> SGPR (wave-uniform via readfirstlane); C -> VGPR, pinned by asm so
    // the compiler cannot sink the LDS loads back into the inner loop.
    float sB[49], vC[49];
    #pragma unroll
    for (int t = 0; t < 49; ++t) {
        v2f wc = swt[t];
        sB[t] = __uint_as_float(__builtin_amdgcn_readfirstlane(__float_as_uint(wc.x)));
        vC[t] = wc.y;
    }
    #pragma unroll
    for (int t = 0; t < 49; ++t) asm volatile("" : "+v"(vC[t]));

    if (lx < 28) {
        const int x0 = lx * 2;    // output col base (even) -> 16B-aligned LDS reads
        const int rb = ty * 7;    // output row base

        float a0x[7], a0y[7], a1x[7], a1y[7];
        #pragma unroll
        for (int r = 0; r < 7; ++r) { a0x[r] = a0y[r] = a1x[r] = a1y[r] = 0.f; }

        #pragma unroll
        for (int ir = 0; ir < 13; ++ir) {
            const v4f* q = (const v4f*)&sp[rb + ir][x0];
            v4f q0 = q[0], q1 = q[1], q2 = q[2], q3 = q[3];
            // pu[k] = u at col x0-3+k, pv[k] = matching v  (k = 0..7)
            float pu[8] = {q0.x, q0.z, q1.x, q1.z, q2.x, q2.z, q3.x, q3.z};
            float pv[8] = {q0.y, q0.w, q1.y, q1.w, q2.y, q2.w, q3.y, q3.w};
            #pragma unroll
            for (int ry = 0; ry < 7; ++ry) {
                const int i = ir - ry;          // weight row; compile-time resolved
                if (i >= 0 && i <= 6) {
                    #pragma unroll
                    for (int j = 0; j < 7; ++j) {
                        const int t = i * 7 + j;
                        a0x[ry] = fmaf(pu[j],     sB[t], a0x[ry]);   // v_fma_f32, SGPR src
                        a0y[ry] = fmaf(pv[j],     vC[t], a0y[ry]);
                        a1x[ry] = fmaf(pu[j + 1], sB[t], a1x[ry]);
                        a1y[ry] = fmaf(pv[j + 1], vC[t], a1y[ry]);
                    }
                }
            }
        }

        #pragma unroll
        for (int ry = 0; ry < 7; ++ry) {
            float2 o = make_float2(a0x[ry] + a0y[ry], a1x[ry] + a1y[ry]);
            *(float2*)&out[plane + (rb + ry) * 56 + x0] = o;
        }
    }
}

extern "C" void kernel_launch(void* const* d_in, const int* in_sizes, int n_in,
                              void* d_out, int out_size, void* d_ws, size_t ws_size,
                              hipStream_t stream) {
    const float* x = (const float*)d_in[0];   // (4,192,56,56) fp32
    const float* w = (const float*)d_in[1];   // (192,1,7,7) fp32
    float* out = (float*)d_out;

    hipLaunchKernelGGL(wconv_kernel, dim3(192, 4), dim3(32, 8), 0, stream, x, w, out);
}

// Round 3
// 78.815 us; speedup vs baseline: 1.2035x; 1.2035x over previous
//
#include <hip/hip_runtime.h>

typedef float v2f __attribute__((ext_vector_type(2)));
typedef float v4f __attribute__((ext_vector_type(4)));

#define EPS 1e-7f
#define SPW 66   // LDS row stride in v2f: 528 B = 33*16 (b128-aligned rows)

// mantissa_map: (|v|+eps) -> mantissa m in [1,2); result = m>=1.5 ? m/2 : m  -> [0.75,1.5)
__device__ __forceinline__ float mant_map(float v) {
    float a = fabsf(v) + EPS;
    unsigned int bi = __float_as_uint(a);
    float m = __uint_as_float((bi & 0x007FFFFFu) | 0x3F800000u);
    return (m >= 1.5f) ? 0.5f * m : m;
}

// R3: one block per (b,c) plane, (32,8)=256 threads, grid (192,4) = 768 blocks
// (3 blocks/CU, 12 waves/CU). Thread (lx<28, ty): out cols {2lx,2lx+1}, rows
// ty*7..ty*7+6. out = sum_taps u*B + v*C, u=x, v=x/M1, B=w/M2, C=B*(M2-1).
//
// vs R0 (~28us kernel): R0 re-read each weight from LDS per use (343 ds_read_b64
// broadcasts/wave) -> LDS-issue-bound. R2 pinned all 49 {B,C} pairs (98 VGPR) and
// SPILLED (VGPR=84, +67MB scratch traffic, 51.7us). R3 splits taps into two
// passes: rows 0..2 (21 v2f regs) then rows 3..6 (28 v2f regs) -> peak ~115 VGPR,
// no spill, v_pk_fma_f32 kept. Weight reads 343->49/thread; input rows re-read
// 13->19 (5 ds-reads each). Staging now ds_write_b128 (halo = 4 cols so interior
// writes are 16B-aligned): 3136->1568 write ops/block.
__global__ __launch_bounds__(256, 3) void wconv_kernel(const float* __restrict__ x,
                                                       const float* __restrict__ w,
                                                       float* __restrict__ out) {
    __shared__ v2f sp[62][SPW];  // LDS row r = input row r-3; v2f col c = input col c-4
    __shared__ v2f swt[49];      // {B, C} per tap

    const int lx = threadIdx.x;   // 0..31 (col pair; compute-active if <28)
    const int ty = threadIdx.y;   // 0..7
    const int tid = ty * 32 + lx;
    const int c = blockIdx.x;
    const int b = blockIdx.y;

    const long plane = (long)(b * 192 + c) * 3136;
    const float* xp = x + plane;

    // --- fused weight prep ---
    if (tid < 49) {
        float wv = w[c * 49 + tid];
        float M2 = mant_map(wv);
        float B = wv / M2;
        swt[tid] = (v2f){B, B * (M2 - 1.0f)};
    }

    // --- halo zero: top rows 0..2, bottom rows 59..61 (full width) ---
    for (int t = tid; t < 3 * SPW; t += 256) {
        ((v2f*)sp)[t] = (v2f){0.f, 0.f};
        ((v2f*)sp)[59 * SPW + t] = (v2f){0.f, 0.f};
    }
    // side cols of the 56 real rows: cols 0..3 (left halo) and 60..62 (right)
    for (int t = tid; t < 392; t += 256) {
        int r = t / 7, k = t % 7;
        int col = (k < 4) ? k : 56 + k;   // 0,1,2,3,60,61,62
        sp[3 + r][col] = (v2f){0.f, 0.f};
    }

    // --- interior staging: 56 rows x 14 quads = 784 tasks, b128 writes ---
    {
        const int t0 = tid, t1 = tid + 256, t2 = tid + 512;
        v4f u0 = *(const v4f*)(xp + (t0 / 14) * 56 + (t0 % 14) * 4);
        v4f u1 = *(const v4f*)(xp + (t1 / 14) * 56 + (t1 % 14) * 4);
        v4f u2 = *(const v4f*)(xp + (t2 / 14) * 56 + (t2 % 14) * 4);
        v4f u3;
        if (tid < 16) u3 = *(const v4f*)(xp + ((tid + 768) / 14) * 56 + ((tid + 768) % 14) * 4);

        auto stage = [&](int t, v4f u4) {
            v4f* dst = (v4f*)&sp[3 + t / 14][4 + (t % 14) * 4];   // byte offset % 16 == 0
            dst[0] = (v4f){u4.x, u4.x * __builtin_amdgcn_rcpf(mant_map(u4.x)),
                           u4.y, u4.y * __builtin_amdgcn_rcpf(mant_map(u4.y))};
            dst[1] = (v4f){u4.z, u4.z * __builtin_amdgcn_rcpf(mant_map(u4.z)),
                           u4.w, u4.w * __builtin_amdgcn_rcpf(mant_map(u4.w))};
        };
        stage(t0, u0);
        stage(t1, u1);
        stage(t2, u2);
        if (tid < 16) stage(tid + 768, u3);
    }
    __syncthreads();

    if (lx < 28) {
        const int x0 = lx * 2;    // even LDS col base; p[j] = LDS col x0+1+j = input col 2lx-3+j
        const int rb = ty * 7;    // output row base

        v2f a0[7], a1[7];
        #pragma unroll
        for (int r = 0; r < 7; ++r) { a0[r] = (v2f){0.f, 0.f}; a1[r] = (v2f){0.f, 0.f}; }

// p[0..7] = {u,v} for input cols 2lx-3 .. 2lx+4 of LDS row RR.
// 1x b64 (odd col, 8B-aligned) + 3x b128 (even cols, 16B-aligned) + 1x b64.
#define LOAD_P(RR, P)                                                   \
        v2f P[8];                                                       \
        {                                                               \
            const v2f* row_ = &sp[(RR)][0];                             \
            P[0] = row_[x0 + 1];                                        \
            v4f q1_ = *(const v4f*)&row_[x0 + 2];                       \
            v4f q2_ = *(const v4f*)&row_[x0 + 4];                       \
            v4f q3_ = *(const v4f*)&row_[x0 + 6];                       \
            P[7] = row_[x0 + 8];                                        \
            P[1] = (v2f){q1_.x, q1_.y}; P[2] = (v2f){q1_.z, q1_.w};     \
            P[3] = (v2f){q2_.x, q2_.y}; P[4] = (v2f){q2_.z, q2_.w};     \
            P[5] = (v2f){q3_.x, q3_.y}; P[6] = (v2f){q3_.z, q3_.w};     \
        }

        // ---- Pass A: weight rows 0..2 resident in 21 v2f regs ----
        {
            v2f wA[21];
            #pragma unroll
            for (int t = 0; t < 21; ++t) wA[t] = swt[t];
            asm("" : "+v"(wA[0]), "+v"(wA[1]), "+v"(wA[2]), "+v"(wA[3]), "+v"(wA[4]),
                     "+v"(wA[5]), "+v"(wA[6]), "+v"(wA[7]), "+v"(wA[8]), "+v"(wA[9]),
                     "+v"(wA[10]), "+v"(wA[11]), "+v"(wA[12]), "+v"(wA[13]), "+v"(wA[14]),
                     "+v"(wA[15]), "+v"(wA[16]), "+v"(wA[17]), "+v"(wA[18]), "+v"(wA[19]),
                     "+v"(wA[20]));
            #pragma unroll
            for (int ir = 0; ir <= 8; ++ir) {
                LOAD_P(rb + ir, p)
                #pragma unroll
                for (int ry = 0; ry < 7; ++ry) {
                    const int i = ir - ry;               // weight row, compile-time
                    if (i >= 0 && i <= 2) {
                        #pragma unroll
                        for (int j = 0; j < 7; ++j) {
                            v2f wc = wA[i * 7 + j];
                            a0[ry] += p[j] * wc;         // v_pk_fma_f32
                            a1[ry] += p[j + 1] * wc;
                        }
                    }
                }
            }
        }

        // ---- Pass B: weight rows 3..6 resident in 28 v2f regs ----
        {
            v2f wB[28];
            #pragma unroll
            for (int t = 0; t < 28; ++t) wB[t] = swt[21 + t];
            asm("" : "+v"(wB[0]), "+v"(wB[1]), "+v"(wB[2]), "+v"(wB[3]), "+v"(wB[4]),
                     "+v"(wB[5]), "+v"(wB[6]), "+v"(wB[7]), "+v"(wB[8]), "+v"(wB[9]),
                     "+v"(wB[10]), "+v"(wB[11]), "+v"(wB[12]), "+v"(wB[13]), "+v"(wB[14]),
                     "+v"(wB[15]), "+v"(wB[16]), "+v"(wB[17]), "+v"(wB[18]), "+v"(wB[19]),
                     "+v"(wB[20]), "+v"(wB[21]), "+v"(wB[22]), "+v"(wB[23]), "+v"(wB[24]),
                     "+v"(wB[25]), "+v"(wB[26]), "+v"(wB[27]));
            #pragma unroll
            for (int ir = 3; ir <= 12; ++ir) {
                LOAD_P(rb + ir, p)
                #pragma unroll
                for (int ry = 0; ry < 7; ++ry) {
                    const int i = ir - ry;
                    if (i >= 3 && i <= 6) {
                        #pragma unroll
                        for (int j = 0; j < 7; ++j) {
                            v2f wc = wB[(i - 3) * 7 + j];
                            a0[ry] += p[j] * wc;
                            a1[ry] += p[j + 1] * wc;
                        }
                    }
                }
            }
        }
#undef LOAD_P

        #pragma unroll
        for (int ry = 0; ry < 7; ++ry) {
            float2 o = make_float2(a0[ry].x + a0[ry].y, a1[ry].x + a1[ry].y);
            *(float2*)&out[plane + (rb + ry) * 56 + x0] = o;
        }
    }
}

extern "C" void kernel_launch(void* const* d_in, const int* in_sizes, int n_in,
                              void* d_out, int out_size, void* d_ws, size_t ws_size,
                              hipStream_t stream) {
    const float* x = (const float*)d_in[0];   // (4,192,56,56) fp32
    const float* w = (const float*)d_in[1];   // (192,1,7,7) fp32
    float* out = (float*)d_out;

    hipLaunchKernelGGL(wconv_kernel, dim3(192, 4), dim3(32, 8), 0, stream, x, w, out);
}